// Round 1
// baseline (431.971 us; speedup 1.0000x reference)
//
#include <hip/hip_runtime.h>

// LIF recurrence + online eligibility-trace gradient, decomposed:
//   u[b,t]  = x[b,t,:] . w                       (pass 1, GEMV, 4 rows/wave)
//   v_t = a*v + u_t - vth*z ; z_t = v>vth        (pass 2: 32 blocks, one batch each)
//   s_t = u_t - v_t*wsq   (== eps@w)
//   q_t = s_{t+1} + a*q_{t+1}; c_t = v_t + q_t
//   gpart[tc,b,n] = sum_{t in tc} c_t x[b,t,n]   (pass 3, NTC=8 partials)
//   g[b,n] = sum_tc gpart - (sum v^2) w[n]       (pass 4 reduce, fused init)
//
// L3 strategy (this revision): x is exactly 256 MiB == Infinity Cache size.
// Pass 1 reads x with REGULAR loads (allocate in L3); pass 3 re-reads it in
// REVERSE order (LIFO vs LRU) with regular loads -> mostly L3 hits.
// Terminal outputs (v, z, g) use nontemporal stores so they don't evict x.
// Intermediates re-read immediately (u, c, gpart) stay regular (L2-served).

#define ALPHA 0.995f
#define VTH   2.0f

constexpr int B = 32;
constexpr int T = 1024;
constexpr int N = 2048;
constexpr int TCH = 128;          // timesteps per accum chunk
constexpr int NTC = T / TCH;      // 8 accum partials

typedef float floatx4 __attribute__((ext_vector_type(4)));

__device__ inline floatx4 load4(const float* p) {
    return *reinterpret_cast<const floatx4*>(p);
}
__device__ inline void ntstore4(float* p, floatx4 v) {
    __builtin_nontemporal_store(v, reinterpret_cast<floatx4*>(p));
}

// ---- Pass 1: u[b*T + t] = dot(x[b,t,:], w). 4 rows per wave, 4 waves/block.
__global__ __launch_bounds__(256) void gemv_kernel(const float* __restrict__ x,
                                                   const float* __restrict__ w,
                                                   float* __restrict__ u) {
    const int wave = threadIdx.x >> 6;
    const int lane = threadIdx.x & 63;
    const int row0 = blockIdx.x * 16 + wave * 4;      // rows in [0, B*T)
    const float* xr = x + (size_t)row0 * N;
    float s0 = 0.f, s1 = 0.f, s2 = 0.f, s3 = 0.f;
#pragma unroll
    for (int k = 0; k < 8; ++k) {
        const int idx = k * 256 + lane * 4;
        const floatx4 wv = load4(w + idx);
        const floatx4 a = load4(xr + idx);            // regular: allocate x in L3
        const floatx4 b = load4(xr + N + idx);
        const floatx4 c = load4(xr + 2 * N + idx);
        const floatx4 d = load4(xr + 3 * N + idx);
        s0 += a.x * wv.x + a.y * wv.y + a.z * wv.z + a.w * wv.w;
        s1 += b.x * wv.x + b.y * wv.y + b.z * wv.z + b.w * wv.w;
        s2 += c.x * wv.x + c.y * wv.y + c.z * wv.z + c.w * wv.w;
        s3 += d.x * wv.x + d.y * wv.y + d.z * wv.z + d.w * wv.w;
    }
#pragma unroll
    for (int off = 32; off; off >>= 1) {
        s0 += __shfl_down(s0, off);
        s1 += __shfl_down(s1, off);
        s2 += __shfl_down(s2, off);
        s3 += __shfl_down(s3, off);
    }
    if (lane == 0) {
        floatx4 r = {s0, s1, s2, s3};
        *reinterpret_cast<floatx4*>(u + row0) = r;   // u re-read by scan: regular
    }
}

// ---- Pass 2: one block per batch (32 blocks x 64 threads), all data in LDS.
__global__ __launch_bounds__(64) void scan_kernel(const float* __restrict__ w,
                                                  const float* __restrict__ u,     // [B][T]
                                                  float* __restrict__ cbuf,        // [B][T]
                                                  float* __restrict__ V2,
                                                  float* __restrict__ out_v,
                                                  float* __restrict__ out_z) {
    __shared__ float u_lds[T];
    __shared__ float v_lds[T];
    __shared__ float s_lds[T];
    __shared__ float c_lds[T];
    const int b    = blockIdx.x;
    const int lane = threadIdx.x;

    // wsq = sum w^2 (wave butterfly; w is 8KB, L1-hot)
    float wacc = 0.f;
#pragma unroll
    for (int i = 0; i < N / 64; ++i) {
        const float wv = w[i * 64 + lane];
        wacc += wv * wv;
    }
#pragma unroll
    for (int off = 32; off; off >>= 1) wacc += __shfl_xor(wacc, off);
    const float wsq = wacc;

    // stage u[b,:] -> LDS (4 x 1KB coalesced float4 loads)
#pragma unroll
    for (int k = 0; k < T / 256; ++k) {
        const int j = (k * 64 + lane) * 4;
        *reinterpret_cast<floatx4*>(&u_lds[j]) = load4(&u[b * T + j]);
    }
    __syncthreads();

    if (lane == 0) {
        float v = 0.f, z = 0.f, v2 = 0.f;
        // ---- forward: chunks of 32 so ds_reads pipeline ahead of the chain
        for (int cc = 0; cc < T / 32; ++cc) {
            const int base = cc * 32;
            floatx4 ub[8];
#pragma unroll
            for (int k = 0; k < 8; ++k)
                ub[k] = *reinterpret_cast<floatx4*>(&u_lds[base + k * 4]);
            floatx4 vb[8], sb[8];
#pragma unroll
            for (int k = 0; k < 8; ++k) {
#pragma unroll
                for (int e = 0; e < 4; ++e) {
                    const float ut = ub[k][e];
                    v = ALPHA * v + ut - VTH * z;
                    z = (v > VTH) ? 1.f : 0.f;
                    vb[k][e] = v;
                    sb[k][e] = ut - v * wsq;
                    v2 += v * v;
                }
            }
#pragma unroll
            for (int k = 0; k < 8; ++k) {
                *reinterpret_cast<floatx4*>(&v_lds[base + k * 4]) = vb[k];
                *reinterpret_cast<floatx4*>(&s_lds[base + k * 4]) = sb[k];
            }
        }
        V2[b] = v2;
        // ---- backward: q_{t-1} = s_t + a*q_t ; c_t = v_t + q_t
        float q = 0.f;
        for (int cc = T / 32 - 1; cc >= 0; --cc) {
            const int base = cc * 32;
            floatx4 sb[8], vb[8], cb[8];
#pragma unroll
            for (int k = 0; k < 8; ++k) {
                sb[k] = *reinterpret_cast<floatx4*>(&s_lds[base + k * 4]);
                vb[k] = *reinterpret_cast<floatx4*>(&v_lds[base + k * 4]);
            }
#pragma unroll
            for (int k = 7; k >= 0; --k) {
#pragma unroll
                for (int e = 3; e >= 0; --e) {
                    cb[k][e] = vb[k][e] + q;
                    q = sb[k][e] + ALPHA * q;
                }
            }
#pragma unroll
            for (int k = 0; k < 8; ++k)
                *reinterpret_cast<floatx4*>(&c_lds[base + k * 4]) = cb[k];
        }
    }
    __syncthreads();

    // writeout: coalesced float4 per array. v/z are terminal -> NT stores
    // (do not evict x from L3). c is re-read by accum -> regular store.
#pragma unroll
    for (int k = 0; k < T / 256; ++k) {
        const int j = (k * 64 + lane) * 4;
        const floatx4 vv = *reinterpret_cast<floatx4*>(&v_lds[j]);
        floatx4 zz;
        zz.x = (vv.x > VTH) ? 1.f : 0.f;
        zz.y = (vv.y > VTH) ? 1.f : 0.f;
        zz.z = (vv.z > VTH) ? 1.f : 0.f;
        zz.w = (vv.w > VTH) ? 1.f : 0.f;
        ntstore4(&out_v[b * T + j], vv);
        ntstore4(&out_z[b * T + j], zz);
        *reinterpret_cast<floatx4*>(&cbuf[b * T + j]) =
            *reinterpret_cast<floatx4*>(&c_lds[j]);
    }
}

// ---- Pass 3: gpart[tc][b][n] = sum_{t in chunk tc} c_t * x[b,t,n].
// grid = (NTC, N/1024, B), block = 256 threads, float4 per thread.
// Traversal is REVERSED vs pass 1 (b desc via block remap, t desc in-loop):
// pass 1 left the tail of x freshest in L3, so LIFO re-read maximizes hits.
__global__ __launch_bounds__(256) void accum_kernel(const float* __restrict__ x,
                                                    const float* __restrict__ c,   // [B][T]
                                                    float* __restrict__ gpart) {
    __shared__ float cs[TCH];
    const int b   = (B - 1) - blockIdx.z;
    const int nc  = blockIdx.y;
    const int tc  = (NTC - 1) - blockIdx.x;
    const int t0  = tc * TCH;
    const int tid = threadIdx.x;
    if (tid < TCH) cs[tid] = c[b * T + t0 + tid];
    __syncthreads();

    const int n = nc * 1024 + tid * 4;
    const float* xb = x + ((size_t)b * T + t0) * N + n;
    floatx4 acc = {0.f, 0.f, 0.f, 0.f};
#pragma unroll 8
    for (int tt = TCH - 1; tt >= 0; --tt) {
        const floatx4 xv = load4(xb + (size_t)tt * N);   // regular: L3-served
        const float cc = cs[tt];
        acc.x += cc * xv.x;
        acc.y += cc * xv.y;
        acc.z += cc * xv.z;
        acc.w += cc * xv.w;
    }
    *reinterpret_cast<floatx4*>(gpart + ((size_t)tc * B + b) * N + n) = acc;
}

// ---- Pass 4: g[b,n] = sum_tc gpart[tc][b][n] - V2[b]*w[n]
__global__ __launch_bounds__(256) void reduce_kernel(const float* __restrict__ gpart,
                                                     const float* __restrict__ w,
                                                     const float* __restrict__ V2,
                                                     float* __restrict__ g) {
    const int i = blockIdx.x * 256 + threadIdx.x;   // [0, B*N)
    const int b = i >> 11;
    const int n = i & (N - 1);
    float acc = -V2[b] * w[n];
#pragma unroll
    for (int tc = 0; tc < NTC; ++tc) acc += gpart[tc * (B * N) + i];
    __builtin_nontemporal_store(acc, &g[i]);        // terminal output
}

extern "C" void kernel_launch(void* const* d_in, const int* in_sizes, int n_in,
                              void* d_out, int out_size, void* d_ws, size_t ws_size,
                              hipStream_t stream) {
    const float* x = (const float*)d_in[0];   // [B, T, N]
    const float* w = (const float*)d_in[1];   // [N]

    float* out   = (float*)d_out;
    float* out_v = out;                 // [B, T]
    float* out_z = out + B * T;         // [B, T]
    float* out_g = out + 2 * B * T;     // [B, N]

    // workspace (floats): u[B*T], c[B*T], V2[B], gpart[NTC*B*N]
    float* u     = (float*)d_ws;
    float* c     = u + B * T;
    float* V2    = c + B * T;
    float* gpart = V2 + B;

    gemv_kernel<<<(B * T) / 16, 256, 0, stream>>>(x, w, u);
    scan_kernel<<<B, 64, 0, stream>>>(w, u, c, V2, out_v, out_z);
    accum_kernel<<<dim3(NTC, N / 1024, B), 256, 0, stream>>>(x, c, gpart);
    reduce_kernel<<<(B * N) / 256, 256, 0, stream>>>(gpart, w, V2, out_g);
}

// Round 2
// 410.880 us; speedup vs baseline: 1.0513x; 1.0513x over previous
//
#include <hip/hip_runtime.h>

// LIF recurrence + online eligibility-trace gradient, decomposed:
//   u[b,t]  = x[b,t,:] . w                       (pass 1, GEMV, 4 rows/wave, NT loads)
//   v_t = a*v + u_t - vth*z ; z_t = v>vth        (pass 2: 32 blocks, one batch each)
//   s_t = u_t - v_t*wsq   (== eps@w)
//   q_t = s_{t+1} + a*q_{t+1}; c_t = v_t + q_t
//   gpart[tc,b,n] = sum_{t in tc} c_t x[b,t,n]   (pass 3, NTC=8 partials)
//   g[b,n] = sum_tc gpart - (sum v^2) w[n]       (pass 4 reduce, fused init)
//
// Measured lesson (round 1): x is flushed from L3 by the harness's 1 GiB
// workspace re-poison fill each iteration, and 256 MiB through a 256 MiB
// cache self-evicts -> regular (allocating) x loads COST 20 us vs NT.
// Both x streams use nontemporal loads; terminal outputs (v,z,g) use
// nontemporal stores; intermediates (u,c,gpart) stay regular (L2-served).

#define ALPHA 0.995f
#define VTH   2.0f

constexpr int B = 32;
constexpr int T = 1024;
constexpr int N = 2048;
constexpr int TCH = 128;          // timesteps per accum chunk
constexpr int NTC = T / TCH;      // 8 accum partials

typedef float floatx4 __attribute__((ext_vector_type(4)));

__device__ inline floatx4 ntload4(const float* p) {
    return __builtin_nontemporal_load(reinterpret_cast<const floatx4*>(p));
}
__device__ inline floatx4 load4(const float* p) {
    return *reinterpret_cast<const floatx4*>(p);
}
__device__ inline void ntstore4(float* p, floatx4 v) {
    __builtin_nontemporal_store(v, reinterpret_cast<floatx4*>(p));
}

// ---- Pass 1: u[b*T + t] = dot(x[b,t,:], w). 4 rows per wave, 4 waves/block.
__global__ __launch_bounds__(256) void gemv_kernel(const float* __restrict__ x,
                                                   const float* __restrict__ w,
                                                   float* __restrict__ u) {
    const int wave = threadIdx.x >> 6;
    const int lane = threadIdx.x & 63;
    const int row0 = blockIdx.x * 16 + wave * 4;      // rows in [0, B*T)
    const float* xr = x + (size_t)row0 * N;
    float s0 = 0.f, s1 = 0.f, s2 = 0.f, s3 = 0.f;
#pragma unroll
    for (int k = 0; k < 8; ++k) {
        const int idx = k * 256 + lane * 4;
        const floatx4 wv = load4(w + idx);
        const floatx4 a = ntload4(xr + idx);
        const floatx4 b = ntload4(xr + N + idx);
        const floatx4 c = ntload4(xr + 2 * N + idx);
        const floatx4 d = ntload4(xr + 3 * N + idx);
        s0 += a.x * wv.x + a.y * wv.y + a.z * wv.z + a.w * wv.w;
        s1 += b.x * wv.x + b.y * wv.y + b.z * wv.z + b.w * wv.w;
        s2 += c.x * wv.x + c.y * wv.y + c.z * wv.z + c.w * wv.w;
        s3 += d.x * wv.x + d.y * wv.y + d.z * wv.z + d.w * wv.w;
    }
#pragma unroll
    for (int off = 32; off; off >>= 1) {
        s0 += __shfl_down(s0, off);
        s1 += __shfl_down(s1, off);
        s2 += __shfl_down(s2, off);
        s3 += __shfl_down(s3, off);
    }
    if (lane == 0) {
        floatx4 r = {s0, s1, s2, s3};
        *reinterpret_cast<floatx4*>(u + row0) = r;   // u re-read by scan: regular
    }
}

// ---- Pass 2: one block per batch (32 blocks x 64 threads), all data in LDS.
__global__ __launch_bounds__(64) void scan_kernel(const float* __restrict__ w,
                                                  const float* __restrict__ u,     // [B][T]
                                                  float* __restrict__ cbuf,        // [B][T]
                                                  float* __restrict__ V2,
                                                  float* __restrict__ out_v,
                                                  float* __restrict__ out_z) {
    __shared__ float u_lds[T];
    __shared__ float v_lds[T];
    __shared__ float s_lds[T];
    __shared__ float c_lds[T];
    const int b    = blockIdx.x;
    const int lane = threadIdx.x;

    // wsq = sum w^2 (wave butterfly; w is 8KB, L1-hot)
    float wacc = 0.f;
#pragma unroll
    for (int i = 0; i < N / 64; ++i) {
        const float wv = w[i * 64 + lane];
        wacc += wv * wv;
    }
#pragma unroll
    for (int off = 32; off; off >>= 1) wacc += __shfl_xor(wacc, off);
    const float wsq = wacc;

    // stage u[b,:] -> LDS (4 x 1KB coalesced float4 loads)
#pragma unroll
    for (int k = 0; k < T / 256; ++k) {
        const int j = (k * 64 + lane) * 4;
        *reinterpret_cast<floatx4*>(&u_lds[j]) = load4(&u[b * T + j]);
    }
    __syncthreads();

    if (lane == 0) {
        float v = 0.f, z = 0.f, v2 = 0.f;
        // ---- forward: chunks of 32 so ds_reads pipeline ahead of the chain
        for (int cc = 0; cc < T / 32; ++cc) {
            const int base = cc * 32;
            floatx4 ub[8];
#pragma unroll
            for (int k = 0; k < 8; ++k)
                ub[k] = *reinterpret_cast<floatx4*>(&u_lds[base + k * 4]);
            floatx4 vb[8], sb[8];
#pragma unroll
            for (int k = 0; k < 8; ++k) {
#pragma unroll
                for (int e = 0; e < 4; ++e) {
                    const float ut = ub[k][e];
                    v = ALPHA * v + ut - VTH * z;
                    z = (v > VTH) ? 1.f : 0.f;
                    vb[k][e] = v;
                    sb[k][e] = ut - v * wsq;
                    v2 += v * v;
                }
            }
#pragma unroll
            for (int k = 0; k < 8; ++k) {
                *reinterpret_cast<floatx4*>(&v_lds[base + k * 4]) = vb[k];
                *reinterpret_cast<floatx4*>(&s_lds[base + k * 4]) = sb[k];
            }
        }
        V2[b] = v2;
        // ---- backward: q_{t-1} = s_t + a*q_t ; c_t = v_t + q_t
        float q = 0.f;
        for (int cc = T / 32 - 1; cc >= 0; --cc) {
            const int base = cc * 32;
            floatx4 sb[8], vb[8], cb[8];
#pragma unroll
            for (int k = 0; k < 8; ++k) {
                sb[k] = *reinterpret_cast<floatx4*>(&s_lds[base + k * 4]);
                vb[k] = *reinterpret_cast<floatx4*>(&v_lds[base + k * 4]);
            }
#pragma unroll
            for (int k = 7; k >= 0; --k) {
#pragma unroll
                for (int e = 3; e >= 0; --e) {
                    cb[k][e] = vb[k][e] + q;
                    q = sb[k][e] + ALPHA * q;
                }
            }
#pragma unroll
            for (int k = 0; k < 8; ++k)
                *reinterpret_cast<floatx4*>(&c_lds[base + k * 4]) = cb[k];
        }
    }
    __syncthreads();

    // writeout: coalesced float4 per array. v/z terminal -> NT stores;
    // c is re-read by accum -> regular store (L2-served).
#pragma unroll
    for (int k = 0; k < T / 256; ++k) {
        const int j = (k * 64 + lane) * 4;
        const floatx4 vv = *reinterpret_cast<floatx4*>(&v_lds[j]);
        floatx4 zz;
        zz.x = (vv.x > VTH) ? 1.f : 0.f;
        zz.y = (vv.y > VTH) ? 1.f : 0.f;
        zz.z = (vv.z > VTH) ? 1.f : 0.f;
        zz.w = (vv.w > VTH) ? 1.f : 0.f;
        ntstore4(&out_v[b * T + j], vv);
        ntstore4(&out_z[b * T + j], zz);
        *reinterpret_cast<floatx4*>(&cbuf[b * T + j]) =
            *reinterpret_cast<floatx4*>(&c_lds[j]);
    }
}

// ---- Pass 3: gpart[tc][b][n] = sum_{t in chunk tc} c_t * x[b,t,n].
// grid = (NTC, N/1024, B), block = 256 threads, float4 per thread.
__global__ __launch_bounds__(256) void accum_kernel(const float* __restrict__ x,
                                                    const float* __restrict__ c,   // [B][T]
                                                    float* __restrict__ gpart) {
    __shared__ float cs[TCH];
    const int b   = blockIdx.z;
    const int nc  = blockIdx.y;
    const int tc  = blockIdx.x;
    const int t0  = tc * TCH;
    const int tid = threadIdx.x;
    if (tid < TCH) cs[tid] = c[b * T + t0 + tid];
    __syncthreads();

    const int n = nc * 1024 + tid * 4;
    const float* xb = x + ((size_t)b * T + t0) * N + n;
    floatx4 acc = {0.f, 0.f, 0.f, 0.f};
#pragma unroll 8
    for (int tt = 0; tt < TCH; ++tt) {
        const floatx4 xv = ntload4(xb + (size_t)tt * N);
        const float cc = cs[tt];
        acc.x += cc * xv.x;
        acc.y += cc * xv.y;
        acc.z += cc * xv.z;
        acc.w += cc * xv.w;
    }
    *reinterpret_cast<floatx4*>(gpart + ((size_t)tc * B + b) * N + n) = acc;
}

// ---- Pass 4: g[b,n] = sum_tc gpart[tc][b][n] - V2[b]*w[n]
__global__ __launch_bounds__(256) void reduce_kernel(const float* __restrict__ gpart,
                                                     const float* __restrict__ w,
                                                     const float* __restrict__ V2,
                                                     float* __restrict__ g) {
    const int i = blockIdx.x * 256 + threadIdx.x;   // [0, B*N)
    const int b = i >> 11;
    const int n = i & (N - 1);
    float acc = -V2[b] * w[n];
#pragma unroll
    for (int tc = 0; tc < NTC; ++tc) acc += gpart[tc * (B * N) + i];
    __builtin_nontemporal_store(acc, &g[i]);        // terminal output
}

extern "C" void kernel_launch(void* const* d_in, const int* in_sizes, int n_in,
                              void* d_out, int out_size, void* d_ws, size_t ws_size,
                              hipStream_t stream) {
    const float* x = (const float*)d_in[0];   // [B, T, N]
    const float* w = (const float*)d_in[1];   // [N]

    float* out   = (float*)d_out;
    float* out_v = out;                 // [B, T]
    float* out_z = out + B * T;         // [B, T]
    float* out_g = out + 2 * B * T;     // [B, N]

    // workspace (floats): u[B*T], c[B*T], V2[B], gpart[NTC*B*N]
    float* u     = (float*)d_ws;
    float* c     = u + B * T;
    float* V2    = c + B * T;
    float* gpart = V2 + B;

    gemv_kernel<<<(B * T) / 16, 256, 0, stream>>>(x, w, u);
    scan_kernel<<<B, 64, 0, stream>>>(w, u, c, V2, out_v, out_z);
    accum_kernel<<<dim3(NTC, N / 1024, B), 256, 0, stream>>>(x, c, gpart);
    reduce_kernel<<<(B * N) / 256, 256, 0, stream>>>(gpart, w, V2, out_g);
}